// Round 19
// baseline (196.558 us; speedup 1.0000x reference)
//
#include <hip/hip_runtime.h>
#include <hip/hip_bf16.h>

#define VOCABN 50000
#define BN 128
#define CN 5
#define HN 50
#define LN 32
#define DN 300
#define DP 320     // padded K
#define KNN 20

typedef __bf16    bf16x8 __attribute__((ext_vector_type(8)));
typedef float     f32x4  __attribute__((ext_vector_type(4)));
typedef float     f32x2  __attribute__((ext_vector_type(2)));
typedef ushort    u16x8  __attribute__((ext_vector_type(8)));

#if __has_builtin(__builtin_amdgcn_exp2f)
#define FEXP2 __builtin_amdgcn_exp2f
#else
#define FEXP2 exp2f
#endif
#if __has_builtin(__builtin_amdgcn_logf)
#define FLOG2 __builtin_amdgcn_logf
#else
#define FLOG2 log2f
#endif

#define LOG2E 1.4426950408889634f
#define LN2F  0.6931471805599453f

// ---------------- kernel 1: normalize vocab -> bf16 table, wave-per-row (R11-proven) ----------------
__global__ __launch_bounds__(256) void knorm_embed2(const float* __restrict__ emb,
                                                    ushort* __restrict__ tabo) {
    const int t    = threadIdx.x;
    const int lane = t & 63;
    const int w    = t >> 6;
    const int v    = blockIdx.x * 4 + w;          // grid 12500 x 4 waves
    const float* row = emb + (size_t)v * DN;
    const float4* r4 = (const float4*)row;

    float4 x = r4[lane];
    float ss = x.x * x.x + x.y * x.y + x.z * x.z + x.w * x.w;
    if (lane < 11) {
        float4 y = r4[64 + lane];
        ss += y.x * y.x + y.y * y.y + y.z * y.z + y.w * y.w;
    }
    #pragma unroll
    for (int off = 32; off; off >>= 1) ss += __shfl_xor(ss, off);
    const float scale = 1.0f / fmaxf(sqrtf(ss), 1e-8f);

    if (lane < 40) {
        u16x8 u;
        #pragma unroll
        for (int j = 0; j < 8; ++j) {
            int e = lane * 8 + j;
            float f = (e < DN) ? row[e] * scale : 0.f;
            __hip_bfloat16 h = __float2bfloat16(f);
            u[j] = *(ushort*)&h;
        }
        *(u16x8*)(tabo + (size_t)v * DP + lane * 8) = u;
    }
}

// ---------------- kernel 2: fused GEMM + pooling, fully wave-autonomous (zero-LDS GEMM) ----------------
// Block = (b,h), 6400 blocks, 320 threads. Each wave free-runs: per-lane direct gathers for
// A and B frags (1-slice-ahead rotation, unrolled K), 4 MFMA/slice, NO barriers after tok.
__global__ __launch_bounds__(320, 6) void knrm_fused10(const int* __restrict__ cand,
                                                       const int* __restrict__ clik,
                                                       const ushort* __restrict__ tab,
                                                       const float* __restrict__ ltr_w,
                                                       float* __restrict__ score) {
    __shared__ __align__(16) char smem[21888];
    // [0, 21120): pool arena, 5 waves x [32][33] f32 (wave-private)
    int* tokA = (int*)(smem + 21120);             // 160 ints
    int* tokB = (int*)(smem + 21760);             // 32 ints

    const int t    = threadIdx.x;
    const int lane = t & 63;
    const int w    = t >> 6;          // wave 0..4 == candidate c
    // T1: bijective XCD swizzle (grid 6400 = 8 x 800); same-b blocks co-XCD
    const int bid  = (blockIdx.x & 7) * 800 + (blockIdx.x >> 3);
    const int b    = bid / HN;
    const int h    = bid % HN;

    if (t < 160)      tokA[t] = cand[b * (CN * LN) + t];
    else if (t < 192) tokB[t - 160] = clik[b * (HN * LN) + h * LN + (t - 160)];
    __syncthreads();                  // the ONLY barrier

    const int m15 = lane & 15;
    const int g4  = lane >> 4;

    // per-lane gather bases (fixed row/chunk; K-step adds ss*64, compile-time immediates)
    const char* sA0 = (const char*)tab + (size_t)tokA[w * 32 + m15]      * (DP * 2) + g4 * 16;
    const char* sA1 = (const char*)tab + (size_t)tokA[w * 32 + 16 + m15] * (DP * 2) + g4 * 16;
    const char* sB0 = (const char*)tab + (size_t)tokB[m15]               * (DP * 2) + g4 * 16;
    const char* sB1 = (const char*)tab + (size_t)tokB[16 + m15]          * (DP * 2) + g4 * 16;

    f32x4 acc[2][2];
    #pragma unroll
    for (int at = 0; at < 2; ++at)
        #pragma unroll
        for (int jg = 0; jg < 2; ++jg)
            acc[at][jg] = (f32x4){0.f, 0.f, 0.f, 0.f};

    // prologue: slice-0 frags
    bf16x8 a0 = *(const bf16x8*)sA0;
    bf16x8 a1 = *(const bf16x8*)sA1;
    bf16x8 b0 = *(const bf16x8*)sB0;
    bf16x8 b1 = *(const bf16x8*)sB1;

    #pragma unroll
    for (int ss = 0; ss < 10; ++ss) {             // 10 K-slices of 32, fully unrolled
        bf16x8 a0c = a0, a1c = a1, b0c = b0, b1c = b1;
        if (ss < 9) {                             // 1-slice-ahead rotation, hides under MFMA
            const int so = (ss + 1) * 64;
            a0 = *(const bf16x8*)(sA0 + so);
            a1 = *(const bf16x8*)(sA1 + so);
            b0 = *(const bf16x8*)(sB0 + so);
            b1 = *(const bf16x8*)(sB1 + so);
        }
        acc[0][0] = __builtin_amdgcn_mfma_f32_16x16x32_bf16(a0c, b0c, acc[0][0], 0, 0, 0);
        acc[0][1] = __builtin_amdgcn_mfma_f32_16x16x32_bf16(a0c, b1c, acc[0][1], 0, 0, 0);
        acc[1][0] = __builtin_amdgcn_mfma_f32_16x16x32_bf16(a1c, b0c, acc[1][0], 0, 0, 0);
        acc[1][1] = __builtin_amdgcn_mfma_f32_16x16x32_bf16(a1c, b1c, acc[1][1], 0, 0, 0);
    }

    // ---- pool: single pass, 32x33 f32 wave-private tile (R17-proven), no barrier needed ----
    const float C1   = 10.0f * LOG2E;
    const float C2   = -50.0f * LOG2E;
    const float AK19 = 849.3218002880191f;  // sqrt(LOG2E / (2*0.001^2))
    static const float CkT[10] = {          // e^{-m^2/2}; unrolled j folds to immediates
        1.0f, 0.6065306597126334f, 0.1353352832366127f, 0.011108996538242306f,
        3.3546262790251185e-4f, 3.7266531720786709e-6f, 1.5229979744712628e-8f,
        2.2897348456191135e-11f, 1.2664165549094176e-14f, 2.576757109154981e-18f };

    float* sb = (float*)(smem + w * 4224);        // [32][33] f32, wave-private

    // dump all 4 tiles: C/D col=lane&15, row=(lane>>4)*4+r [m89-verified]
    #pragma unroll
    for (int at = 0; at < 2; ++at)
        #pragma unroll
        for (int jgl = 0; jgl < 2; ++jgl)
            #pragma unroll
            for (int r = 0; r < 4; ++r)
                sb[(at * 16 + g4 * 4 + r) * 33 + jgl * 16 + m15] = acc[at][jgl][r];
    // wave-internal lgkmcnt ordering makes writes visible to the reads below

    const int hi = lane >> 5;                     // column half owned by this lane
    const float* sp = sb + (lane & 31) * 33 + hi * 16;

    f32x2 Qp[9];                                  // Qp[j-1] = {Q[9+j], Q[9-j]}
    #pragma unroll
    for (int j = 0; j < 9; ++j) Qp[j] = (f32x2){0.f, 0.f};
    float Q9 = 0.f, Q19 = 0.f;

    #pragma unroll
    for (int ec = 0; ec < 4; ++ec) {
        f32x4 v = *(const f32x4*)(sp + ec * 4);
        #pragma unroll
        for (int e = 0; e < 4; ++e) {
            float s  = v[e];
            float cs = C1 * s;
            float tt = FEXP2(cs);
            float uu = FEXP2(-cs);
            float e0 = FEXP2(C2 * (s * s));
            Q9 += e0;
            f32x2 tu = {tt, uu};
            f32x2 pm = {e0, e0};
            #pragma unroll
            for (int j = 0; j < 9; ++j) { pm *= tu; Qp[j] += pm; }  // v_pk_mul/add
            float d = fmaf(s, AK19, -AK19);       // (s-1)*AK19
            Q19 += FEXP2(-(d * d));               // sharp sigma=0.001 kernel
        }
    }

    // single-step pair reduce: lane <-> lane^32 (same row, other column half)
    #pragma unroll
    for (int j = 0; j < 9; ++j) {
        Qp[j].x += __shfl_xor(Qp[j].x, 32);
        Qp[j].y += __shfl_xor(Qp[j].y, 32);
    }
    Q9  += __shfl_xor(Q9, 32);
    Q19 += __shfl_xor(Q19, 32);

    // k-split logs (branchless): hi=0 -> k=0..9 (u-side + Q9), hi=1 -> k=10..19 (t-side + Q19)
    const float* wrow = ltr_w + h * KNN;
    float q0 = hi ? Q19 : Q9;
    float w0 = wrow[hi ? 19 : 9];
    float res = w0 * FLOG2(fmaxf(q0, 1e-10f));
    #pragma unroll
    for (int j = 1; j <= 9; ++j) {
        float q  = hi ? Qp[j - 1].x : Qp[j - 1].y;
        float wk = wrow[hi ? (9 + j) : (9 - j)];
        res += wk * FLOG2(fmaxf(q * CkT[j], 1e-10f));
    }

    res *= LN2F;                                  // each (row,k) counted exactly once
    #pragma unroll
    for (int off = 32; off; off >>= 1) res += __shfl_xor(res, off);
    if (lane == 0) atomicAdd(&score[b * CN + w], res);
}

// ---------------- kernel 3: log_softmax over C (ltr_b cancels) ----------------
__global__ __launch_bounds__(128) void knrm_final(const float* __restrict__ score,
                                                  float* __restrict__ out) {
    int b = threadIdx.x;
    if (b < BN) {
        float s[CN];
        float m = -1e30f;
        #pragma unroll
        for (int c = 0; c < CN; ++c) { s[c] = score[b * CN + c]; m = fmaxf(m, s[c]); }
        float sum = 0.f;
        #pragma unroll
        for (int c = 0; c < CN; ++c) sum += FEXP2((s[c] - m) * LOG2E);
        float lse = m + FLOG2(sum) * LN2F;
        #pragma unroll
        for (int c = 0; c < CN; ++c) out[b * CN + c] = s[c] - lse;
    }
}

extern "C" void kernel_launch(void* const* d_in, const int* in_sizes, int n_in,
                              void* d_out, int out_size, void* d_ws, size_t ws_size,
                              hipStream_t stream) {
    const int*   cand  = (const int*)d_in[0];   // [B,C,L]
    const int*   clik  = (const int*)d_in[1];   // [B,H,L]
    const float* emb   = (const float*)d_in[2]; // [VOCAB,D]
    const float* ltr_w = (const float*)d_in[3]; // [1,H*KN]
    float* out = (float*)d_out;

    const size_t TAB_B = (size_t)VOCABN * DP * 2;   // 32,000,000

    ushort* tab  = (ushort*)d_ws;
    float*  scre = (float*)((char*)d_ws + TAB_B);

    hipMemsetAsync(scre, 0, BN * CN * sizeof(float), stream);
    knorm_embed2<<<VOCABN / 4, 256, 0, stream>>>(emb, tab);
    knrm_fused10<<<BN * HN, 320, 0, stream>>>(cand, clik, tab, ltr_w, scre);
    knrm_final<<<1, 128, 0, stream>>>(scre, out);
}

// Round 20
// 153.578 us; speedup vs baseline: 1.2799x; 1.2799x over previous
//
#include <hip/hip_runtime.h>
#include <hip/hip_bf16.h>

#define VOCABN 50000
#define BN 128
#define CN 5
#define HN 50
#define LN 32
#define DN 300
#define DP 320     // padded K
#define KNN 20

typedef __bf16    bf16x8 __attribute__((ext_vector_type(8)));
typedef float     f32x4  __attribute__((ext_vector_type(4)));
typedef float     f32x2  __attribute__((ext_vector_type(2)));
typedef ushort    u16x8  __attribute__((ext_vector_type(8)));

#if __has_builtin(__builtin_amdgcn_exp2f)
#define FEXP2 __builtin_amdgcn_exp2f
#else
#define FEXP2 exp2f
#endif
#if __has_builtin(__builtin_amdgcn_logf)
#define FLOG2 __builtin_amdgcn_logf
#else
#define FLOG2 log2f
#endif

#define LOG2E 1.4426950408889634f
#define LN2F  0.6931471805599453f

// ---------------- kernel 1: normalize vocab -> bf16 table, wave-per-row (R11-proven) ----------------
__global__ __launch_bounds__(256) void knorm_embed2(const float* __restrict__ emb,
                                                    ushort* __restrict__ tabo) {
    const int t    = threadIdx.x;
    const int lane = t & 63;
    const int w    = t >> 6;
    const int v    = blockIdx.x * 4 + w;          // grid 12500 x 4 waves
    const float* row = emb + (size_t)v * DN;
    const float4* r4 = (const float4*)row;

    float4 x = r4[lane];
    float ss = x.x * x.x + x.y * x.y + x.z * x.z + x.w * x.w;
    if (lane < 11) {
        float4 y = r4[64 + lane];
        ss += y.x * y.x + y.y * y.y + y.z * y.z + y.w * y.w;
    }
    #pragma unroll
    for (int off = 32; off; off >>= 1) ss += __shfl_xor(ss, off);
    const float scale = 1.0f / fmaxf(sqrtf(ss), 1e-8f);

    if (lane < 40) {
        u16x8 u;
        #pragma unroll
        for (int j = 0; j < 8; ++j) {
            int e = lane * 8 + j;
            float f = (e < DN) ? row[e] * scale : 0.f;
            __hip_bfloat16 h = __float2bfloat16(f);
            u[j] = *(ushort*)&h;
        }
        *(u16x8*)(tabo + (size_t)v * DP + lane * 8) = u;
    }
}

// Slice buffers: [row][64 ushorts] = 128B rows; 16B chunks XOR-swizzled (R6/R13-proven):
// LDS holds pre-swizzled data (src chunk c^(row&7), linear dst); reader applies same XOR.
__device__ __forceinline__ bf16x8 ldfrag(const ushort* buf, int row, int chunk) {
    int pos = chunk ^ (row & 7);
    return *(const bf16x8*)((const char*)buf + row * 128 + pos * 16);
}

// ---------------- kernel 2: fused GEMM + pooling, BK=64 double-buffered (5 barrier rounds) ----------------
// Block = (b,h), 6400 blocks, 320 threads, ~50 KB LDS -> 3 blocks/CU.
// Per slice: 5 staging gathers in flight, 8 ds_read + 8 MFMA of cover, 1 barrier.
__global__ __launch_bounds__(320, 3) void knrm_fused11(const int* __restrict__ cand,
                                                       const int* __restrict__ clik,
                                                       const ushort* __restrict__ tab,
                                                       const float* __restrict__ ltr_w,
                                                       float* __restrict__ score) {
    __shared__ __align__(16) char smem[49920];
    ushort* Abuf0 = (ushort*)(smem);              // 20480 B (160 rows x 128B)
    ushort* Abuf1 = (ushort*)(smem + 20480);      // 20480 B
    ushort* Bbuf1 = (ushort*)(smem + 40960);      // 4096 B (32 rows x 128B)
    ushort* Bbuf0 = (ushort*)(smem + 45056);      // 4096 B
    int*    tokA  = (int*)(smem + 49152);         // 160
    int*    tokB  = (int*)(smem + 49792);         // 32
    // pool arenas (dead-region aliases; last slice reads only buf1):
    //   waves 0-3 -> Abuf0 (4 x 4224 = 16896 <= 20480); wave 4 -> Bbuf0+tok (4224 <= 4864)

    const int t    = threadIdx.x;
    const int lane = t & 63;
    const int w    = t >> 6;          // wave 0..4 == candidate c
    // T1: bijective XCD swizzle (grid 6400 = 8 x 800); same-b blocks co-XCD
    const int bid  = (blockIdx.x & 7) * 800 + (blockIdx.x >> 3);
    const int b    = bid / HN;
    const int h    = bid % HN;

    if (t < 160)      tokA[t] = cand[b * (CN * LN) + t];
    else if (t < 192) tokB[t - 160] = clik[b * (HN * LN) + h * LN + (t - 160)];
    __syncthreads();

    const int m15 = lane & 15;
    const int g4  = lane >> 4;

    // hoisted staging geometry (BK=64): A 1280 chunks -> 4/thread; B 256 chunks -> t<256, 1 each.
    // src pre-swizzled (chunk c^(row&7)), dst linear.
    const char* srcA[4]; int dstA[4];
    #pragma unroll
    for (int it = 0; it < 4; ++it) {
        int cid = it * 320 + t, row = cid >> 3, c = cid & 7;
        srcA[it] = (const char*)tab + (size_t)tokA[row] * (DP * 2) + ((c ^ (row & 7)) << 4);
        dstA[it] = row * 128 + c * 16;
    }
    const char* srcB; int dstB;
    {
        int tb = t & 255;
        int row = tb >> 3, c = tb & 7;
        srcB = (const char*)tab + (size_t)tokB[row] * (DP * 2) + ((c ^ (row & 7)) << 4);
        dstB = row * 128 + c * 16;
    }

    f32x4 acc[2][2];
    #pragma unroll
    for (int at = 0; at < 2; ++at)
        #pragma unroll
        for (int jg = 0; jg < 2; ++jg)
            acc[at][jg] = (f32x4){0.f, 0.f, 0.f, 0.f};

    // prologue: stage slice 0 into buf1
    {
        int4 pa0 = *(const int4*)(srcA[0]);
        int4 pa1 = *(const int4*)(srcA[1]);
        int4 pa2 = *(const int4*)(srcA[2]);
        int4 pa3 = *(const int4*)(srcA[3]);
        int4 pb;  if (t < 256) pb = *(const int4*)(srcB);
        *(int4*)((char*)Abuf1 + dstA[0]) = pa0;
        *(int4*)((char*)Abuf1 + dstA[1]) = pa1;
        *(int4*)((char*)Abuf1 + dstA[2]) = pa2;
        *(int4*)((char*)Abuf1 + dstA[3]) = pa3;
        if (t < 256) *(int4*)((char*)Bbuf1 + dstB) = pb;
    }
    __syncthreads();

    #pragma unroll
    for (int ss = 0; ss < 5; ++ss) {              // 5 K-slices of 64; ss even->buf1, odd->buf0
        const ushort* A = (ss & 1) ? Abuf0 : Abuf1;
        const ushort* B = (ss & 1) ? Bbuf0 : Bbuf1;

        // issue next-slice gathers early (5 independent loads; land during 8 MFMA + 8 ds_read)
        int4 pa0, pa1, pa2, pa3, pb;
        if (ss < 4) {
            const int so = (ss + 1) * 128;
            pa0 = *(const int4*)(srcA[0] + so);
            pa1 = *(const int4*)(srcA[1] + so);
            pa2 = *(const int4*)(srcA[2] + so);
            pa3 = *(const int4*)(srcA[3] + so);
            if (t < 256) pb = *(const int4*)(srcB + so);
        }

        // compute slice ss: two K=32 halves, 8 ds_read_b128 + 8 MFMA
        #pragma unroll
        for (int kc = 0; kc < 2; ++kc) {
            bf16x8 af0 = ldfrag(A, w * 32 + m15,      kc * 4 + g4);
            bf16x8 af1 = ldfrag(A, w * 32 + 16 + m15, kc * 4 + g4);
            bf16x8 bf0 = ldfrag(B, m15,      kc * 4 + g4);
            bf16x8 bf1 = ldfrag(B, 16 + m15, kc * 4 + g4);
            acc[0][0] = __builtin_amdgcn_mfma_f32_16x16x32_bf16(af0, bf0, acc[0][0], 0, 0, 0);
            acc[0][1] = __builtin_amdgcn_mfma_f32_16x16x32_bf16(af0, bf1, acc[0][1], 0, 0, 0);
            acc[1][0] = __builtin_amdgcn_mfma_f32_16x16x32_bf16(af1, bf0, acc[1][0], 0, 0, 0);
            acc[1][1] = __builtin_amdgcn_mfma_f32_16x16x32_bf16(af1, bf1, acc[1][1], 0, 0, 0);
        }

        // write next slice into the other buffer, publish with one barrier
        if (ss < 4) {
            char* An = (char*)((ss & 1) ? Abuf1 : Abuf0);
            char* Bn = (char*)((ss & 1) ? Bbuf1 : Bbuf0);
            *(int4*)(An + dstA[0]) = pa0;
            *(int4*)(An + dstA[1]) = pa1;
            *(int4*)(An + dstA[2]) = pa2;
            *(int4*)(An + dstA[3]) = pa3;
            if (t < 256) *(int4*)(Bn + dstB) = pb;
            __syncthreads();
        }
        // ss==4 (reads buf1): no barrier — fall into wave-private pooling on buf0/tok arenas
    }

    // ---- pool: single pass, 32x33 f32 wave-private tile (R17-proven) ----
    const float C1   = 10.0f * LOG2E;
    const float C2   = -50.0f * LOG2E;
    const float AK19 = 849.3218002880191f;  // sqrt(LOG2E / (2*0.001^2))
    static const float CkT[10] = {          // e^{-m^2/2}; unrolled j folds to immediates
        1.0f, 0.6065306597126334f, 0.1353352832366127f, 0.011108996538242306f,
        3.3546262790251185e-4f, 3.7266531720786709e-6f, 1.5229979744712628e-8f,
        2.2897348456191135e-11f, 1.2664165549094176e-14f, 2.576757109154981e-18f };

    float* sb = (w < 4) ? (float*)(smem + w * 4224)          // in Abuf0
                        : (float*)(smem + 45056);            // Bbuf0 + tok spill (dead)
    // dump all 4 tiles: C/D col=lane&15, row=(lane>>4)*4+r [m89-verified]
    #pragma unroll
    for (int at = 0; at < 2; ++at)
        #pragma unroll
        for (int jgl = 0; jgl < 2; ++jgl)
            #pragma unroll
            for (int r = 0; r < 4; ++r)
                sb[(at * 16 + g4 * 4 + r) * 33 + jgl * 16 + m15] = acc[at][jgl][r];
    // wave-internal lgkmcnt ordering makes writes visible to the reads below

    const int hi = lane >> 5;                     // column half owned by this lane
    const float* sp = sb + (lane & 31) * 33 + hi * 16;

    f32x2 Qp[9];                                  // Qp[j-1] = {Q[9+j], Q[9-j]}
    #pragma unroll
    for (int j = 0; j < 9; ++j) Qp[j] = (f32x2){0.f, 0.f};
    float Q9 = 0.f, Q19 = 0.f;

    #pragma unroll
    for (int ec = 0; ec < 4; ++ec) {
        f32x4 v = *(const f32x4*)(sp + ec * 4);
        #pragma unroll
        for (int e = 0; e < 4; ++e) {
            float s  = v[e];
            float cs = C1 * s;
            float tt = FEXP2(cs);
            float uu = FEXP2(-cs);
            float e0 = FEXP2(C2 * (s * s));
            Q9 += e0;
            f32x2 tu = {tt, uu};
            f32x2 pm = {e0, e0};
            #pragma unroll
            for (int j = 0; j < 9; ++j) { pm *= tu; Qp[j] += pm; }  // v_pk_mul/add
            float d = fmaf(s, AK19, -AK19);       // (s-1)*AK19
            Q19 += FEXP2(-(d * d));               // sharp sigma=0.001 kernel
        }
    }

    // single-step pair reduce: lane <-> lane^32 (same row, other column half)
    #pragma unroll
    for (int j = 0; j < 9; ++j) {
        Qp[j].x += __shfl_xor(Qp[j].x, 32);
        Qp[j].y += __shfl_xor(Qp[j].y, 32);
    }
    Q9  += __shfl_xor(Q9, 32);
    Q19 += __shfl_xor(Q19, 32);

    // k-split logs (branchless): hi=0 -> k=0..9 (u-side + Q9), hi=1 -> k=10..19 (t-side + Q19)
    const float* wrow = ltr_w + h * KNN;
    float q0 = hi ? Q19 : Q9;
    float w0 = wrow[hi ? 19 : 9];
    float res = w0 * FLOG2(fmaxf(q0, 1e-10f));
    #pragma unroll
    for (int j = 1; j <= 9; ++j) {
        float q  = hi ? Qp[j - 1].x : Qp[j - 1].y;
        float wk = wrow[hi ? (9 + j) : (9 - j)];
        res += wk * FLOG2(fmaxf(q * CkT[j], 1e-10f));
    }

    res *= LN2F;                                  // each (row,k) counted exactly once
    #pragma unroll
    for (int off = 32; off; off >>= 1) res += __shfl_xor(res, off);
    if (lane == 0) atomicAdd(&score[b * CN + w], res);
}

// ---------------- kernel 3: log_softmax over C (ltr_b cancels) ----------------
__global__ __launch_bounds__(128) void knrm_final(const float* __restrict__ score,
                                                  float* __restrict__ out) {
    int b = threadIdx.x;
    if (b < BN) {
        float s[CN];
        float m = -1e30f;
        #pragma unroll
        for (int c = 0; c < CN; ++c) { s[c] = score[b * CN + c]; m = fmaxf(m, s[c]); }
        float sum = 0.f;
        #pragma unroll
        for (int c = 0; c < CN; ++c) sum += FEXP2((s[c] - m) * LOG2E);
        float lse = m + FLOG2(sum) * LN2F;
        #pragma unroll
        for (int c = 0; c < CN; ++c) out[b * CN + c] = s[c] - lse;
    }
}

extern "C" void kernel_launch(void* const* d_in, const int* in_sizes, int n_in,
                              void* d_out, int out_size, void* d_ws, size_t ws_size,
                              hipStream_t stream) {
    const int*   cand  = (const int*)d_in[0];   // [B,C,L]
    const int*   clik  = (const int*)d_in[1];   // [B,H,L]
    const float* emb   = (const float*)d_in[2]; // [VOCAB,D]
    const float* ltr_w = (const float*)d_in[3]; // [1,H*KN]
    float* out = (float*)d_out;

    const size_t TAB_B = (size_t)VOCABN * DP * 2;   // 32,000,000

    ushort* tab  = (ushort*)d_ws;
    float*  scre = (float*)((char*)d_ws + TAB_B);

    hipMemsetAsync(scre, 0, BN * CN * sizeof(float), stream);
    knorm_embed2<<<VOCABN / 4, 256, 0, stream>>>(emb, tab);
    knrm_fused11<<<BN * HN, 320, 0, stream>>>(cand, clik, tab, ltr_w, scre);
    knrm_final<<<1, 128, 0, stream>>>(scre, out);
}

// Round 21
// 130.814 us; speedup vs baseline: 1.5026x; 1.1740x over previous
//
#include <hip/hip_runtime.h>
#include <hip/hip_bf16.h>

#define VOCABN 50000
#define BN 128
#define CN 5
#define HN 50
#define LN 32
#define DN 300
#define DP 320     // padded K
#define KNN 20

typedef __bf16    bf16x8 __attribute__((ext_vector_type(8)));
typedef float     f32x4  __attribute__((ext_vector_type(4)));
typedef float     f32x2  __attribute__((ext_vector_type(2)));
typedef ushort    u16x8  __attribute__((ext_vector_type(8)));

#if __has_builtin(__builtin_amdgcn_exp2f)
#define FEXP2 __builtin_amdgcn_exp2f
#else
#define FEXP2 exp2f
#endif
#if __has_builtin(__builtin_amdgcn_logf)
#define FLOG2 __builtin_amdgcn_logf
#else
#define FLOG2 log2f
#endif

#define LOG2E 1.4426950408889634f
#define LN2F  0.6931471805599453f

// ---------------- kernel 1: normalize vocab -> bf16 table, wave-per-row (R11-proven) ----------------
__global__ __launch_bounds__(256) void knorm_embed2(const float* __restrict__ emb,
                                                    ushort* __restrict__ tabo) {
    const int t    = threadIdx.x;
    const int lane = t & 63;
    const int w    = t >> 6;
    const int v    = blockIdx.x * 4 + w;          // grid 12500 x 4 waves
    const float* row = emb + (size_t)v * DN;
    const float4* r4 = (const float4*)row;

    float4 x = r4[lane];
    float ss = x.x * x.x + x.y * x.y + x.z * x.z + x.w * x.w;
    if (lane < 11) {
        float4 y = r4[64 + lane];
        ss += y.x * y.x + y.y * y.y + y.z * y.z + y.w * y.w;
    }
    #pragma unroll
    for (int off = 32; off; off >>= 1) ss += __shfl_xor(ss, off);
    const float scale = 1.0f / fmaxf(sqrtf(ss), 1e-8f);

    if (lane < 40) {
        u16x8 u;
        #pragma unroll
        for (int j = 0; j < 8; ++j) {
            int e = lane * 8 + j;
            float f = (e < DN) ? row[e] * scale : 0.f;
            __hip_bfloat16 h = __float2bfloat16(f);
            u[j] = *(ushort*)&h;
        }
        *(u16x8*)(tabo + (size_t)v * DP + lane * 8) = u;
    }
}

// Paired-row LDS layout (BK=32): LDS row R=row>>1 (128B) holds rows 2R (slots 0-3) and
// 2R+1 (slots 4-7); slot XOR'd by R&7 (R16-verified conflict floor).
__device__ __forceinline__ int paddr(int row, int c) {
    return ((row >> 1) << 7) + ((((c + ((row & 1) << 2))) ^ ((row >> 1) & 7)) << 4);
}
__device__ __forceinline__ bf16x8 ldP(const char* buf, int row, int c) {
    return *(const bf16x8*)(buf + paddr(row, c));
}

// ---------------- kernel 2: fused GEMM + pooling, wave-private double-buffers, ZERO barriers ----------------
// Block = (b,h), 6400 blocks, 320 threads. Wave w owns candidate c=w and an 8 KB LDS arena:
// A dbuf (2x2 KB) + B dbuf (2x2 KB). Per slice: cooperative 4-chunk/lane gather -> reg ->
// ds_write (own arena) -> ds_read frags -> 4 MFMA. In-order per-wave DS pipe = no barriers.
__global__ __launch_bounds__(320, 4) void knrm_fused12(const int* __restrict__ cand,
                                                       const int* __restrict__ clik,
                                                       const ushort* __restrict__ tab,
                                                       const float* __restrict__ ltr_w,
                                                       float* __restrict__ score) {
    __shared__ __align__(16) char smem[40960];    // 5 waves x 8192 B

    const int t    = threadIdx.x;
    const int lane = t & 63;
    const int w    = t >> 6;          // wave 0..4 == candidate c
    // T1: bijective XCD swizzle (grid 6400 = 8 x 800); same-b blocks co-XCD
    const int bid  = (blockIdx.x & 7) * 800 + (blockIdx.x >> 3);
    const int b    = bid / HN;
    const int h    = bid % HN;

    char* arena = smem + w * 8192;
    char* Ab[2] = { arena,        arena + 2048 };
    char* Bb[2] = { arena + 4096, arena + 6144 };

    const int m15 = lane & 63 & 15;
    const int g4  = lane >> 4;

    // cooperative staging geometry: slice = 32 rows x 4 chunks(16B) = 128 chunks for A and B;
    // lane stages chunks {lane, 64+lane} of each: rows lane>>2 and 16+(lane>>2), chunk lane&3.
    const int r0 = lane >> 2, c0 = lane & 3;
    const int r1 = 16 + r0;
    // tok values read per-lane from global (L1-hit; no LDS, no barrier)
    const int tA0 = cand[b * (CN * LN) + w * LN + r0];
    const int tA1 = cand[b * (CN * LN) + w * LN + r1];
    const int tB0 = clik[b * (HN * LN) + h * LN + r0];
    const int tB1 = clik[b * (HN * LN) + h * LN + r1];
    const char* sA0 = (const char*)tab + (size_t)tA0 * (DP * 2) + c0 * 16;
    const char* sA1 = (const char*)tab + (size_t)tA1 * (DP * 2) + c0 * 16;
    const char* sB0 = (const char*)tab + (size_t)tB0 * (DP * 2) + c0 * 16;
    const char* sB1 = (const char*)tab + (size_t)tB1 * (DP * 2) + c0 * 16;
    const int dA0 = paddr(r0, c0), dA1 = paddr(r1, c0);
    const int dB0 = paddr(r0, c0), dB1 = paddr(r1, c0);

    f32x4 acc[2][2];
    #pragma unroll
    for (int at = 0; at < 2; ++at)
        #pragma unroll
        for (int jg = 0; jg < 2; ++jg)
            acc[at][jg] = (f32x4){0.f, 0.f, 0.f, 0.f};

    // prologue: slice 0 -> buf0; slice 1 -> regs
    {
        int4 q0 = *(const int4*)sA0;
        int4 q1 = *(const int4*)sA1;
        int4 q2 = *(const int4*)sB0;
        int4 q3 = *(const int4*)sB1;
        *(int4*)(Ab[0] + dA0) = q0;
        *(int4*)(Ab[0] + dA1) = q1;
        *(int4*)(Bb[0] + dB0) = q2;
        *(int4*)(Bb[0] + dB1) = q3;
    }
    int4 p0 = *(const int4*)(sA0 + 64);
    int4 p1 = *(const int4*)(sA1 + 64);
    int4 p2 = *(const int4*)(sB0 + 64);
    int4 p3 = *(const int4*)(sB1 + 64);

    #pragma unroll
    for (int ss = 0; ss < 10; ++ss) {             // 10 K-slices of 32; zero barriers
        const char* A = Ab[ss & 1];
        const char* B = Bb[ss & 1];

        // frag reads (in-order DS: queued behind the writes that filled this buffer)
        bf16x8 af0 = ldP(A, m15,      g4);
        bf16x8 af1 = ldP(A, 16 + m15, g4);
        bf16x8 bf0 = ldP(B, m15,      g4);
        bf16x8 bf1 = ldP(B, 16 + m15, g4);

        // publish slice ss+1 into the other buffer (regs loaded 1 slice ago)
        if (ss < 9) {
            char* An = Ab[(ss + 1) & 1];
            char* Bn = Bb[(ss + 1) & 1];
            *(int4*)(An + dA0) = p0;
            *(int4*)(An + dA1) = p1;
            *(int4*)(Bn + dB0) = p2;
            *(int4*)(Bn + dB1) = p3;
        }
        // issue slice ss+2 gathers (land during this + next slice's compute)
        if (ss < 8) {
            const int so = (ss + 2) * 64;
            p0 = *(const int4*)(sA0 + so);
            p1 = *(const int4*)(sA1 + so);
            p2 = *(const int4*)(sB0 + so);
            p3 = *(const int4*)(sB1 + so);
        }

        acc[0][0] = __builtin_amdgcn_mfma_f32_16x16x32_bf16(af0, bf0, acc[0][0], 0, 0, 0);
        acc[0][1] = __builtin_amdgcn_mfma_f32_16x16x32_bf16(af0, bf1, acc[0][1], 0, 0, 0);
        acc[1][0] = __builtin_amdgcn_mfma_f32_16x16x32_bf16(af1, bf0, acc[1][0], 0, 0, 0);
        acc[1][1] = __builtin_amdgcn_mfma_f32_16x16x32_bf16(af1, bf1, acc[1][1], 0, 0, 0);
    }

    // ---- pool: single pass, 32x33 f32 wave-private tile (R17-proven), no barrier ----
    // sb aliases this wave's own arena (all GEMM reads of it are earlier in the in-order DS pipe)
    const float C1   = 10.0f * LOG2E;
    const float C2   = -50.0f * LOG2E;
    const float AK19 = 849.3218002880191f;  // sqrt(LOG2E / (2*0.001^2))
    static const float CkT[10] = {          // e^{-m^2/2}; unrolled j folds to immediates
        1.0f, 0.6065306597126334f, 0.1353352832366127f, 0.011108996538242306f,
        3.3546262790251185e-4f, 3.7266531720786709e-6f, 1.5229979744712628e-8f,
        2.2897348456191135e-11f, 1.2664165549094176e-14f, 2.576757109154981e-18f };

    float* sb = (float*)arena;                    // [32][33] f32 = 4224 B <= 8192

    // dump all 4 tiles: C/D col=lane&15, row=(lane>>4)*4+r [m89-verified]
    #pragma unroll
    for (int at = 0; at < 2; ++at)
        #pragma unroll
        for (int jgl = 0; jgl < 2; ++jgl)
            #pragma unroll
            for (int r = 0; r < 4; ++r)
                sb[(at * 16 + g4 * 4 + r) * 33 + jgl * 16 + m15] = acc[at][jgl][r];
    // wave-internal lgkmcnt ordering makes writes visible to the reads below

    const int hi = lane >> 5;                     // column half owned by this lane
    const float* sp = sb + (lane & 31) * 33 + hi * 16;

    f32x2 Qp[9];                                  // Qp[j-1] = {Q[9+j], Q[9-j]}
    #pragma unroll
    for (int j = 0; j < 9; ++j) Qp[j] = (f32x2){0.f, 0.f};
    float Q9 = 0.f, Q19 = 0.f;

    #pragma unroll
    for (int ec = 0; ec < 4; ++ec) {
        f32x4 v = *(const f32x4*)(sp + ec * 4);
        #pragma unroll
        for (int e = 0; e < 4; ++e) {
            float s  = v[e];
            float cs = C1 * s;
            float tt = FEXP2(cs);
            float uu = FEXP2(-cs);
            float e0 = FEXP2(C2 * (s * s));
            Q9 += e0;
            f32x2 tu = {tt, uu};
            f32x2 pm = {e0, e0};
            #pragma unroll
            for (int j = 0; j < 9; ++j) { pm *= tu; Qp[j] += pm; }  // v_pk_mul/add
            float d = fmaf(s, AK19, -AK19);       // (s-1)*AK19
            Q19 += FEXP2(-(d * d));               // sharp sigma=0.001 kernel
        }
    }

    // single-step pair reduce: lane <-> lane^32 (same row, other column half)
    #pragma unroll
    for (int j = 0; j < 9; ++j) {
        Qp[j].x += __shfl_xor(Qp[j].x, 32);
        Qp[j].y += __shfl_xor(Qp[j].y, 32);
    }
    Q9  += __shfl_xor(Q9, 32);
    Q19 += __shfl_xor(Q19, 32);

    // k-split logs (branchless): hi=0 -> k=0..9 (u-side + Q9), hi=1 -> k=10..19 (t-side + Q19)
    const float* wrow = ltr_w + h * KNN;
    float q0 = hi ? Q19 : Q9;
    float w0 = wrow[hi ? 19 : 9];
    float res = w0 * FLOG2(fmaxf(q0, 1e-10f));
    #pragma unroll
    for (int j = 1; j <= 9; ++j) {
        float q  = hi ? Qp[j - 1].x : Qp[j - 1].y;
        float wk = wrow[hi ? (9 + j) : (9 - j)];
        res += wk * FLOG2(fmaxf(q * CkT[j], 1e-10f));
    }

    res *= LN2F;                                  // each (row,k) counted exactly once
    #pragma unroll
    for (int off = 32; off; off >>= 1) res += __shfl_xor(res, off);
    if (lane == 0) atomicAdd(&score[b * CN + w], res);
}

// ---------------- kernel 3: log_softmax over C (ltr_b cancels) ----------------
__global__ __launch_bounds__(128) void knrm_final(const float* __restrict__ score,
                                                  float* __restrict__ out) {
    int b = threadIdx.x;
    if (b < BN) {
        float s[CN];
        float m = -1e30f;
        #pragma unroll
        for (int c = 0; c < CN; ++c) { s[c] = score[b * CN + c]; m = fmaxf(m, s[c]); }
        float sum = 0.f;
        #pragma unroll
        for (int c = 0; c < CN; ++c) sum += FEXP2((s[c] - m) * LOG2E);
        float lse = m + FLOG2(sum) * LN2F;
        #pragma unroll
        for (int c = 0; c < CN; ++c) out[b * CN + c] = s[c] - lse;
    }
}

extern "C" void kernel_launch(void* const* d_in, const int* in_sizes, int n_in,
                              void* d_out, int out_size, void* d_ws, size_t ws_size,
                              hipStream_t stream) {
    const int*   cand  = (const int*)d_in[0];   // [B,C,L]
    const int*   clik  = (const int*)d_in[1];   // [B,H,L]
    const float* emb   = (const float*)d_in[2]; // [VOCAB,D]
    const float* ltr_w = (const float*)d_in[3]; // [1,H*KN]
    float* out = (float*)d_out;

    const size_t TAB_B = (size_t)VOCABN * DP * 2;   // 32,000,000

    ushort* tab  = (ushort*)d_ws;
    float*  scre = (float*)((char*)d_ws + TAB_B);

    hipMemsetAsync(scre, 0, BN * CN * sizeof(float), stream);
    knorm_embed2<<<VOCABN / 4, 256, 0, stream>>>(emb, tab);
    knrm_fused12<<<BN * HN, 320, 0, stream>>>(cand, clik, tab, ltr_w, scre);
    knrm_final<<<1, 128, 0, stream>>>(scre, out);
}

// Round 22
// 126.189 us; speedup vs baseline: 1.5576x; 1.0367x over previous
//
#include <hip/hip_runtime.h>
#include <hip/hip_bf16.h>

#define VOCABN 50000
#define BN 128
#define CN 5
#define HN 50
#define LN 32
#define DN 300
#define DP 320     // padded K
#define KNN 20

typedef __bf16    bf16x8 __attribute__((ext_vector_type(8)));
typedef float     f32x4  __attribute__((ext_vector_type(4)));
typedef float     f32x2  __attribute__((ext_vector_type(2)));
typedef ushort    u16x8  __attribute__((ext_vector_type(8)));

#if __has_builtin(__builtin_amdgcn_exp2f)
#define FEXP2 __builtin_amdgcn_exp2f
#else
#define FEXP2 exp2f
#endif
#if __has_builtin(__builtin_amdgcn_logf)
#define FLOG2 __builtin_amdgcn_logf
#else
#define FLOG2 log2f
#endif

#define LOG2E 1.4426950408889634f
#define LN2F  0.6931471805599453f

// ---------------- kernel 1: normalize vocab -> bf16 table + score zero (fold memset) ----------------
__global__ __launch_bounds__(256) void knorm_embed2(const float* __restrict__ emb,
                                                    ushort* __restrict__ tabo,
                                                    float* __restrict__ scre) {
    const int t    = threadIdx.x;
    if (blockIdx.x == 0) {                        // fold score zeroing (640 floats)
        scre[t] = 0.f; scre[t + 256] = 0.f;
        if (t < 128) scre[t + 512] = 0.f;
    }
    const int lane = t & 63;
    const int w    = t >> 6;
    const int v    = blockIdx.x * 4 + w;          // grid 12500 x 4 waves
    const float* row = emb + (size_t)v * DN;
    const float4* r4 = (const float4*)row;

    float4 x = r4[lane];
    float ss = x.x * x.x + x.y * x.y + x.z * x.z + x.w * x.w;
    if (lane < 11) {
        float4 y = r4[64 + lane];
        ss += y.x * y.x + y.y * y.y + y.z * y.z + y.w * y.w;
    }
    #pragma unroll
    for (int off = 32; off; off >>= 1) ss += __shfl_xor(ss, off);
    const float scale = 1.0f / fmaxf(sqrtf(ss), 1e-8f);

    if (lane < 40) {
        u16x8 u;
        #pragma unroll
        for (int j = 0; j < 8; ++j) {
            int e = lane * 8 + j;
            float f = (e < DN) ? row[e] * scale : 0.f;
            __hip_bfloat16 h = __float2bfloat16(f);
            u[j] = *(ushort*)&h;
        }
        *(u16x8*)(tabo + (size_t)v * DP + lane * 8) = u;
    }
}

// Paired-row LDS layout (BK=32): LDS row R=row>>1 (128B) holds rows 2R (slots 0-3) and
// 2R+1 (slots 4-7); slot XOR'd by R&7 (R16-verified conflict floor).
__device__ __forceinline__ int paddr(int row, int c) {
    return ((row >> 1) << 7) + ((((c + ((row & 1) << 2))) ^ ((row >> 1) & 7)) << 4);
}
__device__ __forceinline__ bf16x8 ldP(const char* buf, int row, int c) {
    return *(const bf16x8*)(buf + paddr(row, c));
}

// ---------------- kernel 2: fused GEMM + pooling, single-buffered wave-private LDS, zero barriers ----------------
// Block = (b,h), 6400 blocks, 320 threads, 21.8 KB LDS -> ~6 blocks/CU (~30 waves).
// In-order per-wave DS pipe: ds_read slice ss then ds_write slice ss+1 to the SAME buffer
// is WAR-safe (reads issued first, DS completes in order; compiler keeps aliasing order).
__global__ __launch_bounds__(320, 8) void knrm_fused13(const int* __restrict__ cand,
                                                       const int* __restrict__ clik,
                                                       const ushort* __restrict__ tab,
                                                       const float* __restrict__ ltr_w,
                                                       float* __restrict__ score) {
    __shared__ __align__(16) char smem[21760];    // 5 waves x 4352 B

    const int t    = threadIdx.x;
    const int lane = t & 63;
    const int w    = t >> 6;          // wave 0..4 == candidate c
    // T1: bijective XCD swizzle (grid 6400 = 8 x 800); same-b blocks co-XCD
    const int bid  = (blockIdx.x & 7) * 800 + (blockIdx.x >> 3);
    const int b    = bid / HN;
    const int h    = bid % HN;

    char* arena = smem + w * 4352;
    char* Ab = arena;                 // 2048 B (32 rows paired)
    char* Bb = arena + 2048;          // 2048 B

    const int m15 = lane & 15;
    const int g4  = lane >> 4;

    // cooperative staging geometry: lane stages rows r0=lane>>2, r1=16+r0, chunk c0=lane&3
    const int r0 = lane >> 2, c0 = lane & 3;
    const int r1 = 16 + r0;
    // tok values read per-lane from global (L1-hit; no LDS, no barrier)
    const int tA0 = cand[b * (CN * LN) + w * LN + r0];
    const int tA1 = cand[b * (CN * LN) + w * LN + r1];
    const int tB0 = clik[b * (HN * LN) + h * LN + r0];
    const int tB1 = clik[b * (HN * LN) + h * LN + r1];
    const char* sA0 = (const char*)tab + (size_t)tA0 * (DP * 2) + c0 * 16;
    const char* sA1 = (const char*)tab + (size_t)tA1 * (DP * 2) + c0 * 16;
    const char* sB0 = (const char*)tab + (size_t)tB0 * (DP * 2) + c0 * 16;
    const char* sB1 = (const char*)tab + (size_t)tB1 * (DP * 2) + c0 * 16;
    const int d0 = paddr(r0, c0), d1 = paddr(r1, c0);

    f32x4 acc[2][2];
    #pragma unroll
    for (int at = 0; at < 2; ++at)
        #pragma unroll
        for (int jg = 0; jg < 2; ++jg)
            acc[at][jg] = (f32x4){0.f, 0.f, 0.f, 0.f};

    // prologue: slice 0 -> bufs; slice 1 -> regs
    {
        int4 q0 = *(const int4*)sA0;
        int4 q1 = *(const int4*)sA1;
        int4 q2 = *(const int4*)sB0;
        int4 q3 = *(const int4*)sB1;
        *(int4*)(Ab + d0) = q0;
        *(int4*)(Ab + d1) = q1;
        *(int4*)(Bb + d0) = q2;
        *(int4*)(Bb + d1) = q3;
    }
    int4 p0 = *(const int4*)(sA0 + 64);
    int4 p1 = *(const int4*)(sA1 + 64);
    int4 p2 = *(const int4*)(sB0 + 64);
    int4 p3 = *(const int4*)(sB1 + 64);

    #pragma unroll
    for (int ss = 0; ss < 10; ++ss) {             // 10 K-slices of 32; zero barriers
        // frag reads of slice ss (data written in previous iteration; in-order DS)
        bf16x8 af0 = ldP(Ab, m15,      g4);
        bf16x8 af1 = ldP(Ab, 16 + m15, g4);
        bf16x8 bf0 = ldP(Bb, m15,      g4);
        bf16x8 bf1 = ldP(Bb, 16 + m15, g4);

        // publish slice ss+1 into the SAME buffers (WAR-safe: issued after the reads)
        if (ss < 9) {
            *(int4*)(Ab + d0) = p0;
            *(int4*)(Ab + d1) = p1;
            *(int4*)(Bb + d0) = p2;
            *(int4*)(Bb + d1) = p3;
        }
        // issue slice ss+2 gathers (land during this + next slice's compute)
        if (ss < 8) {
            const int so = (ss + 2) * 64;
            p0 = *(const int4*)(sA0 + so);
            p1 = *(const int4*)(sA1 + so);
            p2 = *(const int4*)(sB0 + so);
            p3 = *(const int4*)(sB1 + so);
        }

        acc[0][0] = __builtin_amdgcn_mfma_f32_16x16x32_bf16(af0, bf0, acc[0][0], 0, 0, 0);
        acc[0][1] = __builtin_amdgcn_mfma_f32_16x16x32_bf16(af0, bf1, acc[0][1], 0, 0, 0);
        acc[1][0] = __builtin_amdgcn_mfma_f32_16x16x32_bf16(af1, bf0, acc[1][0], 0, 0, 0);
        acc[1][1] = __builtin_amdgcn_mfma_f32_16x16x32_bf16(af1, bf1, acc[1][1], 0, 0, 0);
    }

    // ---- pool: single pass, 32x33 f32 wave-private tile (R17-proven), no barrier ----
    // sb aliases this wave's own arena (all GEMM LDS ops are earlier in the in-order DS pipe)
    const float C1   = 10.0f * LOG2E;
    const float C2   = -50.0f * LOG2E;
    const float AK19 = 849.3218002880191f;  // sqrt(LOG2E / (2*0.001^2))
    static const float CkT[10] = {          // e^{-m^2/2}; unrolled j folds to immediates
        1.0f, 0.6065306597126334f, 0.1353352832366127f, 0.011108996538242306f,
        3.3546262790251185e-4f, 3.7266531720786709e-6f, 1.5229979744712628e-8f,
        2.2897348456191135e-11f, 1.2664165549094176e-14f, 2.576757109154981e-18f };

    float* sb = (float*)arena;                    // [32][33] f32 = 4224 B <= 4352

    // dump all 4 tiles: C/D col=lane&15, row=(lane>>4)*4+r [m89-verified]
    #pragma unroll
    for (int at = 0; at < 2; ++at)
        #pragma unroll
        for (int jgl = 0; jgl < 2; ++jgl)
            #pragma unroll
            for (int r = 0; r < 4; ++r)
                sb[(at * 16 + g4 * 4 + r) * 33 + jgl * 16 + m15] = acc[at][jgl][r];
    // wave-internal lgkmcnt ordering makes writes visible to the reads below

    const int hi = lane >> 5;                     // column half owned by this lane
    const float* sp = sb + (lane & 31) * 33 + hi * 16;

    f32x2 Qp[9];                                  // Qp[j-1] = {Q[9+j], Q[9-j]}
    #pragma unroll
    for (int j = 0; j < 9; ++j) Qp[j] = (f32x2){0.f, 0.f};
    float Q9 = 0.f, Q19 = 0.f;

    #pragma unroll
    for (int ec = 0; ec < 4; ++ec) {
        f32x4 v = *(const f32x4*)(sp + ec * 4);
        #pragma unroll
        for (int e = 0; e < 4; ++e) {
            float s  = v[e];
            float cs = C1 * s;
            float tt = FEXP2(cs);
            float uu = FEXP2(-cs);
            float e0 = FEXP2(C2 * (s * s));
            Q9 += e0;
            f32x2 tu = {tt, uu};
            f32x2 pm = {e0, e0};
            #pragma unroll
            for (int j = 0; j < 9; ++j) { pm *= tu; Qp[j] += pm; }  // v_pk_mul/add
        }
        // sharp sigma=0.001 kernel fires only near s=1 (token match); skipped chunks
        // contribute < 2^-72 each (reference: < exp(-50), also -> 1e-10 clip). ~99% skip.
        float m4 = fmaxf(fmaxf(v[0], v[1]), fmaxf(v[2], v[3]));
        if (__any(m4 > 0.99f)) {
            #pragma unroll
            for (int e = 0; e < 4; ++e) {
                float d = fmaf(v[e], AK19, -AK19);    // (s-1)*AK19
                Q19 += FEXP2(-(d * d));
            }
        }
    }

    // single-step pair reduce: lane <-> lane^32 (same row, other column half)
    #pragma unroll
    for (int j = 0; j < 9; ++j) {
        Qp[j].x += __shfl_xor(Qp[j].x, 32);
        Qp[j].y += __shfl_xor(Qp[j].y, 32);
    }
    Q9  += __shfl_xor(Q9, 32);
    Q19 += __shfl_xor(Q19, 32);

    // k-split logs (branchless): hi=0 -> k=0..9 (u-side + Q9), hi=1 -> k=10..19 (t-side + Q19)
    const float* wrow = ltr_w + h * KNN;
    float q0 = hi ? Q19 : Q9;
    float w0 = wrow[hi ? 19 : 9];
    float res = w0 * FLOG2(fmaxf(q0, 1e-10f));
    #pragma unroll
    for (int j = 1; j <= 9; ++j) {
        float q  = hi ? Qp[j - 1].x : Qp[j - 1].y;
        float wk = wrow[hi ? (9 + j) : (9 - j)];
        res += wk * FLOG2(fmaxf(q * CkT[j], 1e-10f));
    }

    res *= LN2F;                                  // each (row,k) counted exactly once
    #pragma unroll
    for (int off = 32; off; off >>= 1) res += __shfl_xor(res, off);
    if (lane == 0) atomicAdd(&score[b * CN + w], res);
}

// ---------------- kernel 3: log_softmax over C (ltr_b cancels) ----------------
__global__ __launch_bounds__(128) void knrm_final(const float* __restrict__ score,
                                                  float* __restrict__ out) {
    int b = threadIdx.x;
    if (b < BN) {
        float s[CN];
        float m = -1e30f;
        #pragma unroll
        for (int c = 0; c < CN; ++c) { s[c] = score[b * CN + c]; m = fmaxf(m, s[c]); }
        float sum = 0.f;
        #pragma unroll
        for (int c = 0; c < CN; ++c) sum += FEXP2((s[c] - m) * LOG2E);
        float lse = m + FLOG2(sum) * LN2F;
        #pragma unroll
        for (int c = 0; c < CN; ++c) out[b * CN + c] = s[c] - lse;
    }
}

extern "C" void kernel_launch(void* const* d_in, const int* in_sizes, int n_in,
                              void* d_out, int out_size, void* d_ws, size_t ws_size,
                              hipStream_t stream) {
    const int*   cand  = (const int*)d_in[0];   // [B,C,L]
    const int*   clik  = (const int*)d_in[1];   // [B,H,L]
    const float* emb   = (const float*)d_in[2]; // [VOCAB,D]
    const float* ltr_w = (const float*)d_in[3]; // [1,H*KN]
    float* out = (float*)d_out;

    const size_t TAB_B = (size_t)VOCABN * DP * 2;   // 32,000,000

    ushort* tab  = (ushort*)d_ws;
    float*  scre = (float*)((char*)d_ws + TAB_B);

    knorm_embed2<<<VOCABN / 4, 256, 0, stream>>>(emb, tab, scre);
    knrm_fused13<<<BN * HN, 320, 0, stream>>>(cand, clik, tab, ltr_w, scre);
    knrm_final<<<1, 128, 0, stream>>>(scre, out);
}